// Round 7
// baseline (945.770 us; speedup 1.0000x reference)
//
#include <hip/hip_runtime.h>
#include <hip/hip_bf16.h>

typedef unsigned int uint32;
using short8 = __attribute__((ext_vector_type(8))) short;
using ushort4_t = __attribute__((ext_vector_type(4))) unsigned short;
using f32x4  = __attribute__((ext_vector_type(4))) float;

#define B_ 32
#define C_ 256
#define M_ 4096
#define MATF 2097152      // elements per 32-batch matrix set (32*256*256)

#define AS1 __attribute__((address_space(1)))
#define AS3 __attribute__((address_space(3)))

__device__ inline ushort f2bf(float f) {
  __hip_bfloat16 h = __float2bfloat16(f);
  return __builtin_bit_cast(unsigned short, h);
}
__device__ inline float bf2f(ushort u) {
  uint32 v = ((uint32)u) << 16;
  return __builtin_bit_cast(float, v);
}
__device__ inline void gl_lds16(const ushort* g, ushort* l) {
  __builtin_amdgcn_global_load_lds((const AS1 void*)g, (AS3 void*)l, 16, 0, 0);
}

// ---------------------------------------------------------------------------
// covpool partial (round-3 proven): slice s of Gram G[b] = X X^T over
// k = s*512..+512. One block = full 256x256 output from one shared LDS panel.
// grid 256 (32 b x 8 s), 1024 threads (16 waves, each a 64x64 quadrant).
// ---------------------------------------------------------------------------
__global__ __launch_bounds__(1024)
void covpool_kernel(const float* __restrict__ x, float* __restrict__ parts,
                    float* __restrict__ rs) {
  const int bid = blockIdx.x;
  const int b = bid >> 3, s = bid & 7;
  const int kb = s * 512;
  const float* Xb = x + (size_t)b * C_ * M_;
  float* P = parts + (size_t)s * MATF + ((size_t)b << 16);

  __shared__ ushort As[256 * 64];   // 32 KB

  const int t    = threadIdx.x;
  const int lane = t & 63;
  const int w    = t >> 6;            // 0..15
  const int wr   = w >> 2, wc = w & 3;
  const int row  = t >> 2;            // 0..255
  const int ch   = t & 3;             // 16-float source chunk

  float rsum = 0.f;
  f32x4 acc[4][4];
#pragma unroll
  for (int m = 0; m < 4; ++m)
#pragma unroll
    for (int n = 0; n < 4; ++n) acc[m][n] = f32x4{0.f, 0.f, 0.f, 0.f};

  const int swzbase = (row & 7) << 4;
  char* wbase = (char*)As + row * 128;

  for (int k0 = kb; k0 < kb + 512; k0 += 64) {
    __syncthreads();
    const float* src = Xb + (size_t)row * M_ + k0 + ch * 16;
    const float4 v0 = ((const float4*)src)[0];
    const float4 v1 = ((const float4*)src)[1];
    const float4 v2 = ((const float4*)src)[2];
    const float4 v3 = ((const float4*)src)[3];
    rsum += v0.x + v0.y + v0.z + v0.w + v1.x + v1.y + v1.z + v1.w +
            v2.x + v2.y + v2.z + v2.w + v3.x + v3.y + v3.z + v3.w;
    short8 h0, h1;
    h0[0] = (short)f2bf(v0.x); h0[1] = (short)f2bf(v0.y);
    h0[2] = (short)f2bf(v0.z); h0[3] = (short)f2bf(v0.w);
    h0[4] = (short)f2bf(v1.x); h0[5] = (short)f2bf(v1.y);
    h0[6] = (short)f2bf(v1.z); h0[7] = (short)f2bf(v1.w);
    h1[0] = (short)f2bf(v2.x); h1[1] = (short)f2bf(v2.y);
    h1[2] = (short)f2bf(v2.z); h1[3] = (short)f2bf(v2.w);
    h1[4] = (short)f2bf(v3.x); h1[5] = (short)f2bf(v3.y);
    h1[6] = (short)f2bf(v3.z); h1[7] = (short)f2bf(v3.w);
    const int c0 = ch * 2;
    *(short8*)(wbase + ((c0 * 16) ^ swzbase))       = h0;
    *(short8*)(wbase + (((c0 + 1) * 16) ^ swzbase)) = h1;
    __syncthreads();
#pragma unroll
    for (int kk = 0; kk < 2; ++kk) {
      short8 af[4], bfr[4];
      const int slot = kk * 4 + (lane >> 4);
#pragma unroll
      for (int m = 0; m < 4; ++m) {
        const int ar = wr * 64 + m * 16 + (lane & 15);
        af[m] = *(const short8*)((const char*)As + ar * 128 + ((slot * 16) ^ ((ar & 7) << 4)));
      }
#pragma unroll
      for (int n = 0; n < 4; ++n) {
        const int br = wc * 64 + n * 16 + (lane & 15);
        bfr[n] = *(const short8*)((const char*)As + br * 128 + ((slot * 16) ^ ((br & 7) << 4)));
      }
#pragma unroll
      for (int m = 0; m < 4; ++m)
#pragma unroll
        for (int n = 0; n < 4; ++n)
          acc[m][n] = __builtin_amdgcn_mfma_f32_16x16x32_bf16(af[m], bfr[n], acc[m][n], 0, 0, 0);
    }
  }

  rsum += __shfl_xor(rsum, 1);
  rsum += __shfl_xor(rsum, 2);
  if (ch == 0) rs[b * 2048 + s * 256 + row] = rsum;

#pragma unroll
  for (int m = 0; m < 4; ++m)
#pragma unroll
    for (int n = 0; n < 4; ++n)
#pragma unroll
      for (int r = 0; r < 4; ++r) {
        const int lr = wr * 64 + m * 16 + ((lane >> 4) * 4) + r;
        const int lc = wc * 64 + n * 16 + (lane & 15);
        P[(size_t)lr * C_ + lc] = acc[m][n][r];
      }
}

// ---------------------------------------------------------------------------
// trace from partials: n = sum_i (G_ii/M - mu_i^2); invn, sqrtn
// ---------------------------------------------------------------------------
__global__ __launch_bounds__(256)
void trace_kernel(const float* __restrict__ parts, const float* __restrict__ rs,
                  float* __restrict__ invn, float* __restrict__ sqrtn) {
  const int b = blockIdx.x;
  const int i = threadIdx.x;
  const float invM = 1.0f / (float)M_;
  float d = 0.f, m = 0.f;
#pragma unroll
  for (int s = 0; s < 8; ++s) {
    d += parts[(size_t)s * MATF + ((size_t)b << 16) + (size_t)i * 257];
    m += rs[b * 2048 + s * 256 + i];
  }
  const float mu = m * invM;
  float v = d * invM - mu * mu;
#pragma unroll
  for (int o = 32; o > 0; o >>= 1) v += __shfl_xor(v, o);
  __shared__ float wsum[4];
  if ((i & 63) == 0) wsum[i >> 6] = v;
  __syncthreads();
  if (i == 0) {
    const float n = wsum[0] + wsum[1] + wsum[2] + wsum[3];
    invn[b]  = 1.0f / n;
    sqrtn[b] = sqrtf(n);
  }
}

// ---------------------------------------------------------------------------
// reduceprep: cov = (sum_s p_s)/M - mu mu^T (never stored);
// E0 = cov * invn (bf16, trace-normalized)
// ---------------------------------------------------------------------------
__global__ __launch_bounds__(256)
void reduceprep_kernel(const float* __restrict__ parts, const float* __restrict__ rs,
                       const float* __restrict__ invn, ushort* __restrict__ E0) {
  const int idx = blockIdx.x * 256 + threadIdx.x;   // 524288 float4
  const int b   = idx >> 14;
  const int rem = idx & 16383;
  const int i   = rem >> 6;
  const int j   = (rem & 63) * 4;
  const float invM = 1.0f / (float)M_;
  const float4* p4 = (const float4*)parts;

  float4 g = {0.f, 0.f, 0.f, 0.f};
  float  mi = 0.f;
  float4 mj = {0.f, 0.f, 0.f, 0.f};
#pragma unroll
  for (int s = 0; s < 8; ++s) {
    const float4 gs = p4[(size_t)s * (MATF / 4) + idx];
    g.x += gs.x; g.y += gs.y; g.z += gs.z; g.w += gs.w;
    const float* rrow = rs + b * 2048 + s * 256;
    mi += rrow[i];
    const float4 ms = *(const float4*)(rrow + j);
    mj.x += ms.x; mj.y += ms.y; mj.z += ms.z; mj.w += ms.w;
  }
  mi *= invM;
  const float in = invn[b];
  ushort4_t ev;
  ev[0] = f2bf((g.x * invM - mi * (mj.x * invM)) * in);
  ev[1] = f2bf((g.y * invM - mi * (mj.y * invM)) * in);
  ev[2] = f2bf((g.z * invM - mi * (mj.z * invM)) * in);
  ev[3] = f2bf((g.w * invM - mi * (mj.w * invM)) * in);
  ((ushort4_t*)E0)[idx] = ev;
}

// ---------------------------------------------------------------------------
// Per-batch sense-reversing barrier (16 blocks per batch, agent scope).
// bar[0]=arrival count, bar[1]=generation. Assumes all blocks co-resident
// (grid 512 <= 2 blocks/CU capacity).
// ---------------------------------------------------------------------------
__device__ inline void batch_barrier(uint32* bar) {
  __syncthreads();
  if (threadIdx.x == 0) {
    __threadfence();   // release prior global writes to agent scope
    const uint32 g = __hip_atomic_load(&bar[1], __ATOMIC_RELAXED, __HIP_MEMORY_SCOPE_AGENT);
    const uint32 arr = __hip_atomic_fetch_add(&bar[0], 1u, __ATOMIC_ACQ_REL, __HIP_MEMORY_SCOPE_AGENT);
    if (arr == 15u) {
      __hip_atomic_store(&bar[0], 0u, __ATOMIC_RELAXED, __HIP_MEMORY_SCOPE_AGENT);
      __hip_atomic_fetch_add(&bar[1], 1u, __ATOMIC_RELEASE, __HIP_MEMORY_SCOPE_AGENT);
    } else {
      while (__hip_atomic_load(&bar[1], __ATOMIC_ACQUIRE, __HIP_MEMORY_SCOPE_AGENT) == g) {
        __builtin_amdgcn_s_sleep(4);
      }
    }
    __threadfence();   // acquire: make peers' writes visible
  }
  __syncthreads();
}

// ---------------------------------------------------------------------------
// mm_i0 tile unit (R3-proven inner loop): computes 64x64 tile (rb,cb) of
//   O = 1.5*A - 0.5 * (A @ B)  for symmetric B read row-major.
// Arows = A + rb*256, Brows = B + cb*256. LDS As/Bs 8 KB each, 256 threads.
// ---------------------------------------------------------------------------
__device__ __forceinline__ void mm_i0(const ushort* __restrict__ Arows,
                                      const ushort* __restrict__ Brows,
                                      ushort* __restrict__ O,
                                      int rb, int cb,
                                      ushort* As, ushort* Bs, int t) {
  const int lane = t & 63;
  const int wid  = t >> 6;
  const int wr   = wid >> 1, wc = wid & 1;
  const int srow0 = t >> 3;
  const int sc0   = (t & 7) ^ (srow0 & 7);
  const int srow1 = 32 + srow0;
  const int sc1   = (t & 7) ^ (srow1 & 7);

  f32x4 acc[2][2];
#pragma unroll
  for (int m = 0; m < 2; ++m)
#pragma unroll
    for (int n = 0; n < 2; ++n) acc[m][n] = f32x4{0.f, 0.f, 0.f, 0.f};

#pragma unroll
  for (int k0 = 0; k0 < 256; k0 += 64) {
    __syncthreads();
    gl_lds16(Arows + (size_t)srow0 * 256 + k0 + sc0 * 8, As + wid * 512);
    gl_lds16(Arows + (size_t)srow1 * 256 + k0 + sc1 * 8, As + 2048 + wid * 512);
    gl_lds16(Brows + (size_t)srow0 * 256 + k0 + sc0 * 8, Bs + wid * 512);
    gl_lds16(Brows + (size_t)srow1 * 256 + k0 + sc1 * 8, Bs + 2048 + wid * 512);
    __syncthreads();
#pragma unroll
    for (int kk = 0; kk < 2; ++kk) {
      short8 af[2], bfr[2];
      const int slot = kk * 4 + (lane >> 4);
#pragma unroll
      for (int m = 0; m < 2; ++m) {
        const int ar = wr * 32 + m * 16 + (lane & 15);
        af[m] = *(const short8*)((const char*)As + ar * 128 + ((slot * 16) ^ ((ar & 7) << 4)));
      }
#pragma unroll
      for (int n = 0; n < 2; ++n) {
        const int br = wc * 32 + n * 16 + (lane & 15);
        bfr[n] = *(const short8*)((const char*)Bs + br * 128 + ((slot * 16) ^ ((br & 7) << 4)));
      }
#pragma unroll
      for (int m = 0; m < 2; ++m)
#pragma unroll
        for (int n = 0; n < 2; ++n)
          acc[m][n] = __builtin_amdgcn_mfma_f32_16x16x32_bf16(af[m], bfr[n], acc[m][n], 0, 0, 0);
    }
  }

#pragma unroll
  for (int m = 0; m < 2; ++m)
#pragma unroll
    for (int n = 0; n < 2; ++n)
#pragma unroll
      for (int r = 0; r < 4; ++r) {
        const int lr = wr * 32 + m * 16 + ((lane >> 4) * 4) + r;
        const int lc = wc * 32 + n * 16 + (lane & 15);
        const float o = 1.5f * bf2f(Arows[(size_t)lr * 256 + cb + lc]) - 0.5f * acc[m][n][r];
        O[(size_t)(rb + lr) * 256 + cb + lc] = f2bf(o);
      }
}

// ---------------------------------------------------------------------------
// ns_kernel: whole E-form NS chain in ONE dispatch. 512 blocks x 256 thr;
// block -> (xcd = bid&7, b = xcd + 8*(wdx>>4), tile = wdx&15), so each
// batch's 16 tile-blocks share one XCD's L2. Per k=0..3:
//   U  = 1.5 E - 0.5 E@E          (+ tile0: w_{k+1} = 1.5 w_k - 0.5 E w_k)
//   E' = 1.5 U - 0.5 U@E
// with per-batch device barriers between half-steps. Tail (tile0): w5,
// v = sqrtn*(E0 w5), MLP -> a[b].
// ---------------------------------------------------------------------------
__global__ __launch_bounds__(256)
void ns_kernel(const ushort* __restrict__ E0g, ushort* __restrict__ Eag,
               ushort* __restrict__ Ebg, ushort* __restrict__ Ug,
               const float* __restrict__ sqrtn,
               const float* __restrict__ w1, const float* __restrict__ b1,
               const float* __restrict__ w2, const float* __restrict__ b2,
               float* __restrict__ a, uint32* __restrict__ bars) {
  const int bid  = blockIdx.x;
  const int xcd  = bid & 7;
  const int wdx  = bid >> 3;            // 0..63
  const int b    = xcd + 8 * (wdx >> 4);
  const int tile = wdx & 15;
  const int rb   = (tile >> 2) * 64;
  const int cb   = (tile & 3) * 64;
  const size_t off = (size_t)b << 16;
  const ushort* E0 = E0g + off;
  ushort* EA = Eag + off;
  ushort* EB = Ebg + off;
  ushort* U  = Ug  + off;
  uint32* bar = bars + b * 16;

  __shared__ ushort As[64 * 64], Bs[64 * 64];
  __shared__ float wv[2][C_], vv[C_], hh[32];

  const int t = threadIdx.x;
  if (tile == 0) wv[0][t] = 1.0f / (float)C_;

  const ushort* Ecur = E0;
  int p = 0;
#pragma unroll 1
  for (int k = 0; k < 4; ++k) {
    // U = 1.5 E - 0.5 E@E
    mm_i0(Ecur + (size_t)rb * 256, Ecur + (size_t)cb * 256, U, rb, cb, As, Bs, t);
    if (tile == 0) {
      // w_{k+1} = 1.5 w_k - 0.5 * Ecur @ w_k (Ecur symmetric: read row t)
      float accv = 0.f;
      const ushort* Er = Ecur + (size_t)t * 256;
#pragma unroll 4
      for (int kk = 0; kk < 256; kk += 8) {
        const short8 e = *(const short8*)(Er + kk);
#pragma unroll
        for (int u = 0; u < 8; ++u) accv += bf2f((ushort)e[u]) * wv[p][kk + u];
      }
      wv[p ^ 1][t] = 1.5f * wv[p][t] - 0.5f * accv;
    }
    batch_barrier(bar);
    // E' = 1.5 U - 0.5 U@E
    ushort* En = (k & 1) ? EB : EA;
    mm_i0(U + (size_t)rb * 256, Ecur + (size_t)cb * 256, En, rb, cb, As, Bs, t);
    batch_barrier(bar);
    Ecur = En;
    p ^= 1;
  }

  if (tile == 0) {
    // w5 = 1.5 w4 - 0.5 E4 w4
    {
      float accv = 0.f;
      const ushort* Er = Ecur + (size_t)t * 256;
#pragma unroll 4
      for (int kk = 0; kk < 256; kk += 8) {
        const short8 e = *(const short8*)(Er + kk);
#pragma unroll
        for (int u = 0; u < 8; ++u) accv += bf2f((ushort)e[u]) * wv[p][kk + u];
      }
      wv[p ^ 1][t] = 1.5f * wv[p][t] - 0.5f * accv;
    }
    __syncthreads();
    // v = sqrtn * (E0 @ w5)
    {
      float accv = 0.f;
      const ushort* Er = E0 + (size_t)t * 256;
#pragma unroll 4
      for (int kk = 0; kk < 256; kk += 8) {
        const short8 e = *(const short8*)(Er + kk);
#pragma unroll
        for (int u = 0; u < 8; ++u) accv += bf2f((ushort)e[u]) * wv[p ^ 1][kk + u];
      }
      vv[t] = accv * sqrtn[b];
    }
    __syncthreads();
    if (t < 32) {
      float h = b1[t];
      for (int kk = 0; kk < C_; ++kk) h += w1[t * C_ + kk] * vv[kk];
      hh[t] = fmaxf(h, 0.0f);
    }
    __syncthreads();
    float aa = b2[t];
#pragma unroll
    for (int o = 0; o < 32; ++o) aa += w2[t * 32 + o] * hh[o];
    a[b * C_ + t] = 1.0f / (1.0f + expf(-aa));
  }
}

// ---------------------------------------------------------------------------
// scale: out = a[b][c] * x  (nontemporal stores via ext-vector type)
// ---------------------------------------------------------------------------
__global__ __launch_bounds__(256)
void scale_kernel(const float* __restrict__ x, const float* __restrict__ a,
                  float* __restrict__ out) {
  const int stride = gridDim.x * blockDim.x;
  const int n4 = B_ * C_ * M_ / 4;   // 8388608
  const f32x4* xv = (const f32x4*)x;
  f32x4* ov = (f32x4*)out;
  for (int i = blockIdx.x * blockDim.x + threadIdx.x; i < n4; i += stride) {
    const f32x4 v = xv[i];
    const float s = a[i >> 10];
    f32x4 o = { v[0] * s, v[1] * s, v[2] * s, v[3] * s };
    __builtin_nontemporal_store(o, &ov[i]);
  }
}

// ---------------------------------------------------------------------------
extern "C" void kernel_launch(void* const* d_in, const int* in_sizes, int n_in,
                              void* d_out, int out_size, void* d_ws, size_t ws_size,
                              hipStream_t stream) {
  const float* x  = (const float*)d_in[0];
  const float* w1 = (const float*)d_in[1];
  const float* b1 = (const float*)d_in[2];
  const float* w2 = (const float*)d_in[3];
  const float* b2 = (const float*)d_in[4];
  float* out = (float*)d_out;

  float* ws = (float*)d_ws;
  float* parts = ws;                              // 8*MATF fp32 (67 MB)
  float* rs    = ws + 8 * (size_t)MATF;           // 32*2048 fp32
  float* invn  = rs + 65536;
  float* sqrtn = invn + 32;
  float* a     = sqrtn + 32;                      // 32*256
  ushort* E0 = (ushort*)(a + 8192);               // each MATF ushorts (4 MB)
  ushort* Ea = E0 + (size_t)MATF;
  ushort* Eb = Ea + (size_t)MATF;
  ushort* U  = Eb + (size_t)MATF;
  uint32* bars = (uint32*)(U + (size_t)MATF);     // 32 batches * 16 uints

  covpool_kernel<<<256, 1024, 0, stream>>>(x, parts, rs);
  trace_kernel<<<32, 256, 0, stream>>>(parts, rs, invn, sqrtn);
  reduceprep_kernel<<<2048, 256, 0, stream>>>(parts, rs, invn, E0);
  (void)hipMemsetAsync((void*)bars, 0, 32 * 16 * sizeof(uint32), stream);
  ns_kernel<<<512, 256, 0, stream>>>(E0, Ea, Eb, U, sqrtn, w1, b1, w2, b2, a, bars);
  scale_kernel<<<4096, 256, 0, stream>>>(x, a, out);
}